// Round 7
// baseline (317.071 us; speedup 1.0000x reference)
//
#include <hip/hip_runtime.h>

#define DIN 256
#define DH  64
#define DOUT 4

typedef __attribute__((ext_vector_type(8))) short bf16x8;
typedef __attribute__((ext_vector_type(4))) float f32x4;

__device__ __forceinline__ short f2bf(float f) {       // RNE (used in wprep only)
    unsigned int u = __float_as_uint(f);
    unsigned int r = (u + 0x7FFFu + ((u >> 16) & 1u)) >> 16;
    return (short)r;
}
__device__ __forceinline__ short f2bf_trunc(float f) { // truncate mantissa
    return (short)(__float_as_uint(f) >> 16);
}
__device__ __forceinline__ float bf2f(short h) {
    return __uint_as_float(((unsigned int)(unsigned short)h) << 16);
}

// ===========================================================================
// CSR build: count -> 2-level exclusive scan -> fill
// ===========================================================================
__global__ void count_kernel(const int* __restrict__ dst, int* __restrict__ cnt, int E) {
    int e = blockIdx.x * blockDim.x + threadIdx.x;
    if (e < E) atomicAdd(&cnt[dst[e]], 1);
}

__global__ void scan_a_kernel(const int* __restrict__ cnt, int* __restrict__ blocksum, int N) {
    __shared__ int s[256];
    const int t = threadIdx.x;
    const int gi = blockIdx.x * 256 + t;
    s[t] = (gi < N) ? cnt[gi] : 0;
    __syncthreads();
    for (int stp = 128; stp > 0; stp >>= 1) {
        if (t < stp) s[t] += s[t + stp];
        __syncthreads();
    }
    if (t == 0) blocksum[blockIdx.x] = s[0];
}

__global__ void scan_b_kernel(int* __restrict__ blocksum, int* __restrict__ blockoff, int nblk) {
    __shared__ int s[1024];
    const int t = threadIdx.x;
    int v = (t < nblk) ? blocksum[t] : 0;
    s[t] = v;
    __syncthreads();
    for (int stp = 1; stp < 1024; stp <<= 1) {
        int add = (t >= stp) ? s[t - stp] : 0;
        __syncthreads();
        s[t] += add;
        __syncthreads();
    }
    if (t < nblk) blockoff[t] = s[t] - v;   // exclusive
}

__global__ void scan_c_kernel(const int* __restrict__ cnt, const int* __restrict__ blockoff,
                              int* __restrict__ off, int N) {
    __shared__ int s[256];
    const int t = threadIdx.x;
    const int gi = blockIdx.x * 256 + t;
    int v = (gi < N) ? cnt[gi] : 0;
    s[t] = v;
    __syncthreads();
    for (int stp = 1; stp < 256; stp <<= 1) {
        int add = (t >= stp) ? s[t - stp] : 0;
        __syncthreads();
        s[t] += add;
        __syncthreads();
    }
    if (gi <= N) off[gi] = blockoff[blockIdx.x] + s[t] - v;   // exclusive
}

__global__ void fill_kernel(const int* __restrict__ src, const int* __restrict__ dst,
                            const int* __restrict__ off, int* __restrict__ cursor,
                            int* __restrict__ nbr, int E) {
    int e = blockIdx.x * blockDim.x + threadIdx.x;
    if (e >= E) return;
    const int d = dst[e];
    const int p = atomicAdd(&cursor[d], 1);
    nbr[off[d] + p] = src[e];
}

// ===========================================================================
// W prep: split [W1_l | W1_r]^T into hi/lo bf16: WT[n][k], n=0..127, k=0..255
// ===========================================================================
__global__ void wprep_kernel(const float* __restrict__ Wl, const float* __restrict__ Wr,
                             short* __restrict__ WTh, short* __restrict__ WTl) {
    const int k = threadIdx.x;   // 0..255
    const int n = blockIdx.x;    // 0..127
    const float v = (n < 64) ? Wl[k * 64 + n] : Wr[k * 64 + (n - 64)];
    const short hi = f2bf(v);
    const short lo = f2bf(v - bf2f(hi));
    WTh[n * 256 + k] = hi;
    WTl[n * 256 + k] = lo;
}

// ===========================================================================
// GEMM1 v3 (split-bf16 MFMA, barrier-free): y[N,128] = x[N,256] @ [W1l|W1r]
// Each WAVE independently owns 32 rows x 128 cols: 2 M-tiles x 8 N-tiles of
// 16x16x32. No LDS, no __syncthreads. A loaded straight from x (HBM,
// prefetched one K-chunk ahead); B from L2-resident preconverted WTh/WTl
// (prefetched one N-tile ahead). K fully unrolled (8 chunks of 32).
// ===========================================================================
__global__ __launch_bounds__(256, 3) void gemm1_mfma(
    const float* __restrict__ x, const short* __restrict__ WTh,
    const short* __restrict__ WTl, float* __restrict__ y, int N)
{
    const int tid  = threadIdx.x;
    const int wave = tid >> 6;
    const int lane = tid & 63;
    const int lm   = lane & 15;
    const int quad = lane >> 4;
    const int wrow = blockIdx.x * 128 + wave * 32;   // wave's first row

    // A rows for the 2 M-tiles (clamped for loads; stores guarded later)
    const int r0 = wrow + lm;
    const int r1 = wrow + 16 + lm;
    const float* xp0 = x + (size_t)((r0 < N) ? r0 : (N - 1)) * DIN + quad * 8;
    const float* xp1 = x + (size_t)((r1 < N) ? r1 : (N - 1)) * DIN + quad * 8;

    f32x4 acc[2][8];
    #pragma unroll
    for (int mt = 0; mt < 2; ++mt)
        #pragma unroll
        for (int nt = 0; nt < 8; ++nt)
            acc[mt][nt] = (f32x4){0.f, 0.f, 0.f, 0.f};

    // ---- prologue: A chunk 0 in flight
    float4 a0a = ((const float4*)xp0)[0];
    float4 a0b = ((const float4*)xp0)[1];
    float4 a1a = ((const float4*)xp1)[0];
    float4 a1b = ((const float4*)xp1)[1];

    #pragma unroll
    for (int k = 0; k < 8; ++k) {
        // ---- prefetch A chunk k+1 (HBM ~900cyc; hidden by this chunk's MFMAs)
        float4 n0a, n0b, n1a, n1b;
        if (k < 7) {
            const int kc = (k + 1) * 32;
            n0a = ((const float4*)(xp0 + kc))[0];
            n0b = ((const float4*)(xp0 + kc))[1];
            n1a = ((const float4*)(xp1 + kc))[0];
            n1b = ((const float4*)(xp1 + kc))[1];
        }

        // ---- convert chunk k A to split bf16 fragments
        bf16x8 ah0, al0, ah1, al1;
        {
            float f0[8] = {a0a.x, a0a.y, a0a.z, a0a.w, a0b.x, a0b.y, a0b.z, a0b.w};
            float f1[8] = {a1a.x, a1a.y, a1a.z, a1a.w, a1b.x, a1b.y, a1b.z, a1b.w};
            #pragma unroll
            for (int j = 0; j < 8; ++j) {
                short h0 = f2bf_trunc(f0[j]);
                ah0[j] = h0;
                al0[j] = f2bf_trunc(f0[j] - bf2f(h0));
                short h1 = f2bf_trunc(f1[j]);
                ah1[j] = h1;
                al1[j] = f2bf_trunc(f1[j] - bf2f(h1));
            }
        }

        // ---- B: prefetch one N-tile ahead, 6 MFMAs per N-tile
        const int kc = k * 32 + quad * 8;
        bf16x8 bh = *(const bf16x8*)(WTh + (size_t)lm * 256 + kc);
        bf16x8 bl = *(const bf16x8*)(WTl + (size_t)lm * 256 + kc);
        #pragma unroll
        for (int nt = 0; nt < 8; ++nt) {
            bf16x8 bh_n, bl_n;
            if (nt < 7) {
                const size_t wb = (size_t)((nt + 1) * 16 + lm) * 256 + kc;
                bh_n = *(const bf16x8*)(WTh + wb);
                bl_n = *(const bf16x8*)(WTl + wb);
            }
            acc[0][nt] = __builtin_amdgcn_mfma_f32_16x16x32_bf16(ah0, bh, acc[0][nt], 0, 0, 0);
            acc[0][nt] = __builtin_amdgcn_mfma_f32_16x16x32_bf16(ah0, bl, acc[0][nt], 0, 0, 0);
            acc[0][nt] = __builtin_amdgcn_mfma_f32_16x16x32_bf16(al0, bh, acc[0][nt], 0, 0, 0);
            acc[1][nt] = __builtin_amdgcn_mfma_f32_16x16x32_bf16(ah1, bh, acc[1][nt], 0, 0, 0);
            acc[1][nt] = __builtin_amdgcn_mfma_f32_16x16x32_bf16(ah1, bl, acc[1][nt], 0, 0, 0);
            acc[1][nt] = __builtin_amdgcn_mfma_f32_16x16x32_bf16(al1, bh, acc[1][nt], 0, 0, 0);
            bh = bh_n; bl = bl_n;
        }

        // ---- rotate A prefetch
        if (k < 7) { a0a = n0a; a0b = n0b; a1a = n1a; a1b = n1b; }
    }

    // ---- epilogue: C/D layout col=lane&15, row=quad*4+reg
    #pragma unroll
    for (int mt = 0; mt < 2; ++mt) {
        #pragma unroll
        for (int r = 0; r < 4; ++r) {
            const int rg = wrow + mt * 16 + quad * 4 + r;
            if (rg < N) {
                float* yp = y + (size_t)rg * 128 + lm;
                #pragma unroll
                for (int nt = 0; nt < 8; ++nt)
                    yp[nt * 16] = acc[mt][nt][r];
            }
        }
    }
}

// ===========================================================================
// fused1: per node (one wave each):
//   agg = mean_{s in N(i)} y_l[s]; v = agg + b1 + y_r[i]; h = relu(normalize(v));
//   z[i] = [h @ W2_l | h @ W2_r]
// ===========================================================================
__global__ __launch_bounds__(256) void fused1_kernel(
    const float* __restrict__ y, const int* __restrict__ off, const int* __restrict__ nbr,
    const float* __restrict__ b1, const float* __restrict__ W2l, const float* __restrict__ W2r,
    float* __restrict__ z, int N)
{
    const int wave = threadIdx.x >> 6;
    const int lane = threadIdx.x & 63;
    const int i = blockIdx.x * 4 + wave;
    if (i >= N) return;

    const int beg = off[i];
    const int end = off[i + 1];
    const int deg = end - beg;

    const int dd = (deg < 64) ? deg : 64;
    int myn = (lane < dd) ? nbr[beg + lane] : 0;

    float acc = 0.f;
    int j = 0;
    for (; j + 1 < dd; j += 2) {
        const int s0 = __shfl(myn, j, 64);
        const int s1 = __shfl(myn, j + 1, 64);
        const float v0 = y[(size_t)s0 * 128 + lane];
        const float v1 = y[(size_t)s1 * 128 + lane];
        acc += v0 + v1;
    }
    if (j < dd) {
        const int s0 = __shfl(myn, j, 64);
        acc += y[(size_t)s0 * 128 + lane];
    }
    for (int q = beg + 64; q < end; ++q) {
        const int s = nbr[q];
        acc += y[(size_t)s * 128 + lane];
    }

    const float dinv = 1.0f / fmaxf((float)deg, 1.0f);
    float v = acc * dinv + b1[lane] + y[(size_t)i * 128 + 64 + lane];

    float ss = v * v;
    #pragma unroll
    for (int m = 32; m >= 1; m >>= 1) ss += __shfl_xor(ss, m, 64);
    const float inv = 1.0f / fmaxf(sqrtf(ss), 1e-12f);
    const float hv = fmaxf(v * inv, 0.f);

    const float4 wl = *(const float4*)(W2l + lane * 4);
    const float4 wr = *(const float4*)(W2r + lane * 4);
    float p0 = hv * wl.x, p1 = hv * wl.y, p2 = hv * wl.z, p3 = hv * wl.w;
    float p4 = hv * wr.x, p5 = hv * wr.y, p6 = hv * wr.z, p7 = hv * wr.w;

    const bool b0 = (lane & 1) != 0;
    float s0_ = b0 ? p0 : p4;
    float s1_ = b0 ? p1 : p5;
    float s2_ = b0 ? p2 : p6;
    float s3_ = b0 ? p3 : p7;
    float q0 = (b0 ? p4 : p0) + __shfl_xor(s0_, 1, 64);
    float q1 = (b0 ? p5 : p1) + __shfl_xor(s1_, 1, 64);
    float q2 = (b0 ? p6 : p2) + __shfl_xor(s2_, 1, 64);
    float q3 = (b0 ? p7 : p3) + __shfl_xor(s3_, 1, 64);
    const bool b1b = (lane & 2) != 0;
    float t0 = b1b ? q0 : q2;
    float t1 = b1b ? q1 : q3;
    float r0 = (b1b ? q2 : q0) + __shfl_xor(t0, 2, 64);
    float r1 = (b1b ? q3 : q1) + __shfl_xor(t1, 2, 64);
    const bool b2 = (lane & 4) != 0;
    float u0 = b2 ? r0 : r1;
    float zv = (b2 ? r1 : r0) + __shfl_xor(u0, 4, 64);
    zv += __shfl_xor(zv, 8, 64);
    zv += __shfl_xor(zv, 16, 64);
    zv += __shfl_xor(zv, 32, 64);
    const int ch = 4 * (lane & 1) + ((lane & 2)) + ((lane >> 2) & 1);
    if (lane < 8) z[(size_t)i * 8 + ch] = zv;
}

// ===========================================================================
// fused2: per node (one thread): out = normalize(mean z_l[nbr] + b2 + z_r[i])
// ===========================================================================
__global__ void fused2_kernel(const float* __restrict__ z, const int* __restrict__ off,
                              const int* __restrict__ nbr, const float* __restrict__ b2,
                              float* __restrict__ out, int N)
{
    const int i = blockIdx.x * blockDim.x + threadIdx.x;
    if (i >= N) return;
    const int beg = off[i];
    const int end = off[i + 1];
    float4 acc = make_float4(0.f, 0.f, 0.f, 0.f);
    for (int j = beg; j < end; ++j) {
        const int s = nbr[j];
        const float4 t = *(const float4*)(z + (size_t)s * 8);
        acc.x += t.x; acc.y += t.y; acc.z += t.z; acc.w += t.w;
    }
    const float dinv = 1.0f / fmaxf((float)(end - beg), 1.0f);
    const float4 r  = *(const float4*)(z + (size_t)i * 8 + 4);
    const float4 bb = *(const float4*)(b2);
    float4 o;
    o.x = acc.x * dinv + bb.x + r.x;
    o.y = acc.y * dinv + bb.y + r.y;
    o.z = acc.z * dinv + bb.z + r.z;
    o.w = acc.w * dinv + bb.w + r.w;
    const float ss = o.x * o.x + o.y * o.y + o.z * o.z + o.w * o.w;
    const float inv = 1.0f / fmaxf(sqrtf(ss), 1e-12f);
    o.x *= inv; o.y *= inv; o.z *= inv; o.w *= inv;
    *(float4*)(out + (size_t)i * 4) = o;
}

// ===========================================================================
extern "C" void kernel_launch(void* const* d_in, const int* in_sizes, int n_in,
                              void* d_out, int out_size, void* d_ws, size_t ws_size,
                              hipStream_t stream)
{
    const float* x    = (const float*)d_in[0];
    const int*   ei   = (const int*)d_in[1];
    const float* W1l  = (const float*)d_in[2];
    const float* b1l  = (const float*)d_in[3];
    const float* W1r  = (const float*)d_in[4];
    const float* W2l  = (const float*)d_in[5];
    const float* b2l  = (const float*)d_in[6];
    const float* W2r  = (const float*)d_in[7];
    float* out = (float*)d_out;

    const int N = in_sizes[0] / DIN;
    const int E = in_sizes[1] / 2;
    const int* src = ei;
    const int* dst = ei + E;
    const int nblk = (N + 255) / 256;

    // workspace layout
    char* ws = (char*)d_ws;
    size_t woff = 0;
    auto alloc = [&](size_t bytes) {
        void* p = ws + woff;
        woff += (bytes + 255) & ~(size_t)255;
        return p;
    };
    float* y        = (float*)alloc((size_t)N * 128 * 4);
    float* z        = (float*)alloc((size_t)N * 8 * 4);
    short* WTh      = (short*)alloc((size_t)128 * 256 * 2);
    short* WTl      = (short*)alloc((size_t)128 * 256 * 2);
    int*   cnt      = (int*)alloc((size_t)2 * N * 4);    // cnt + cursor contiguous
    int*   cursor   = cnt + N;
    int*   off      = (int*)alloc((size_t)(N + 1) * 4);
    int*   nbr      = (int*)alloc((size_t)E * 4);
    int*   blocksum = (int*)alloc((size_t)nblk * 4);
    int*   blockoff = (int*)alloc((size_t)nblk * 4);

    hipMemsetAsync(cnt, 0, (size_t)2 * N * 4, stream);

    // --- CSR build
    count_kernel<<<(E + 255) / 256, 256, 0, stream>>>(dst, cnt, E);
    scan_a_kernel<<<nblk, 256, 0, stream>>>(cnt, blocksum, N);
    scan_b_kernel<<<1, 1024, 0, stream>>>(blocksum, blockoff, nblk);
    scan_c_kernel<<<nblk, 256, 0, stream>>>(cnt, blockoff, off, N);
    fill_kernel<<<(E + 255) / 256, 256, 0, stream>>>(src, dst, off, cursor, nbr, E);

    // --- layer 1 GEMM
    wprep_kernel<<<128, 256, 0, stream>>>(W1l, W1r, WTh, WTl);
    gemm1_mfma<<<(N + 127) / 128, 256, 0, stream>>>(x, WTh, WTl, y, N);

    // --- fused aggregate + norm + relu + gemm2
    fused1_kernel<<<(N + 3) / 4, 256, 0, stream>>>(y, off, nbr, b1l, W2l, W2r, z, N);

    // --- fused aggregate + norm (layer 2)
    fused2_kernel<<<(N + 255) / 256, 256, 0, stream>>>(z, off, nbr, b2l, out, N);
}

// Round 8
// 285.490 us; speedup vs baseline: 1.1106x; 1.1106x over previous
//
#include <hip/hip_runtime.h>

#define DIN 256
#define DH  64
#define DOUT 4

typedef __attribute__((ext_vector_type(8))) short bf16x8;
typedef __attribute__((ext_vector_type(4))) float f32x4;

__device__ __forceinline__ short f2bf(float f) {       // RNE (wprep only)
    unsigned int u = __float_as_uint(f);
    unsigned int r = (u + 0x7FFFu + ((u >> 16) & 1u)) >> 16;
    return (short)r;
}
__device__ __forceinline__ short f2bf_trunc(float f) { // truncate mantissa
    return (short)(__float_as_uint(f) >> 16);
}
__device__ __forceinline__ float bf2f(short h) {
    return __uint_as_float(((unsigned int)(unsigned short)h) << 16);
}

// ===========================================================================
// CSR build: count -> 2-level exclusive scan -> fill
// ===========================================================================
__global__ void count_kernel(const int* __restrict__ dst, int* __restrict__ cnt, int E) {
    int e = blockIdx.x * blockDim.x + threadIdx.x;
    if (e < E) atomicAdd(&cnt[dst[e]], 1);
}

__global__ void scan_a_kernel(const int* __restrict__ cnt, int* __restrict__ blocksum, int N) {
    __shared__ int s[256];
    const int t = threadIdx.x;
    const int gi = blockIdx.x * 256 + t;
    s[t] = (gi < N) ? cnt[gi] : 0;
    __syncthreads();
    for (int stp = 128; stp > 0; stp >>= 1) {
        if (t < stp) s[t] += s[t + stp];
        __syncthreads();
    }
    if (t == 0) blocksum[blockIdx.x] = s[0];
}

__global__ void scan_b_kernel(int* __restrict__ blocksum, int* __restrict__ blockoff, int nblk) {
    __shared__ int s[1024];
    const int t = threadIdx.x;
    int v = (t < nblk) ? blocksum[t] : 0;
    s[t] = v;
    __syncthreads();
    for (int stp = 1; stp < 1024; stp <<= 1) {
        int add = (t >= stp) ? s[t - stp] : 0;
        __syncthreads();
        s[t] += add;
        __syncthreads();
    }
    if (t < nblk) blockoff[t] = s[t] - v;   // exclusive
}

__global__ void scan_c_kernel(const int* __restrict__ cnt, const int* __restrict__ blockoff,
                              int* __restrict__ off, int N) {
    __shared__ int s[256];
    const int t = threadIdx.x;
    const int gi = blockIdx.x * 256 + t;
    int v = (gi < N) ? cnt[gi] : 0;
    s[t] = v;
    __syncthreads();
    for (int stp = 1; stp < 256; stp <<= 1) {
        int add = (t >= stp) ? s[t - stp] : 0;
        __syncthreads();
        s[t] += add;
        __syncthreads();
    }
    if (gi <= N) off[gi] = blockoff[blockIdx.x] + s[t] - v;   // exclusive
}

__global__ void fill_kernel(const int* __restrict__ src, const int* __restrict__ dst,
                            const int* __restrict__ off, int* __restrict__ cursor,
                            int* __restrict__ nbr, int E) {
    int e = blockIdx.x * blockDim.x + threadIdx.x;
    if (e >= E) return;
    const int d = dst[e];
    const int p = atomicAdd(&cursor[d], 1);
    nbr[off[d] + p] = src[e];
}

// ===========================================================================
// W prep: split [W1_l | W1_r]^T into hi/lo bf16, packed FRAGMENT-CONTIGUOUS:
//   WP[(nt*8 + chunk)*512 + lane*8 + j] where lane = quad*16 + lm encodes
//   (col = nt*16+lm, k = chunk*32 + quad*8 + j). B loads become wave-coalesced.
// ===========================================================================
__global__ void wprep_kernel(const float* __restrict__ Wl, const float* __restrict__ Wr,
                             short* __restrict__ WPh, short* __restrict__ WPl) {
    const int k = threadIdx.x;   // 0..255
    const int n = blockIdx.x;    // 0..127
    const float v = (n < 64) ? Wl[k * 64 + n] : Wr[k * 64 + (n - 64)];
    const short hi = f2bf(v);
    const short lo = f2bf(v - bf2f(hi));
    const int nt = n >> 4, lm = n & 15;
    const int ch = k >> 5, kin = k & 31, quad = kin >> 3, j = kin & 7;
    const int lane = quad * 16 + lm;
    const int idx = nt * 4096 + ch * 512 + lane * 8 + j;
    WPh[idx] = hi;
    WPl[idx] = lo;
}

// ===========================================================================
// GEMM1 v4 (split-bf16 MFMA, BARRIER-FREE): y[N,128] = x[N,256] @ [W1l|W1r]
// Wave-private: each wave owns 16 rows x 128 cols (8 N-tiles, acc=32).
// x staged via wave-private LDS (ds ops = lgkmcnt only -> NO __syncthreads,
// no vmcnt(0) drains). B from packed fragment-contiguous WPh/WPl (L1/L2-hot,
// coalesced). x loaded in 2 half-K bursts (contiguous 512B/row segments) so
// B loads queue behind at most one HBM burst (vmcnt is in-order per wave).
// ===========================================================================
#define A_LD 136   // 128 + 8 pad (shorts); 272 B row stride, 16B-aligned
__global__ __launch_bounds__(256, 4) void gemm1_mfma(
    const float* __restrict__ x, const short* __restrict__ WPh,
    const short* __restrict__ WPl, float* __restrict__ y, int N)
{
    __shared__ short lds[4 * 2 * 16 * A_LD];   // 34816 B, wave-private regions

    const int tid  = threadIdx.x;
    const int wave = tid >> 6;
    const int lane = tid & 63;
    const int lm   = lane & 15;
    const int quad = lane >> 4;
    const int wrow = blockIdx.x * 64 + wave * 16;

    short* Ah = lds + wave * (2 * 16 * A_LD);
    short* Al = Ah + 16 * A_LD;

    // burst layout: lane covers row (lane>>3), k-span (lane&7)*16..+16 floats
    const int brow_l = lane >> 3;          // 0..7
    const int bk     = (lane & 7) * 16;    // float offset within 128-k half

    int g0 = wrow + brow_l;      if (g0 >= N) g0 = N - 1;
    int g1 = wrow + 8 + brow_l;  if (g1 >= N) g1 = N - 1;
    const float* xp0 = x + (size_t)g0 * DIN + bk;
    const float* xp1 = x + (size_t)g1 * DIN + bk;

    f32x4 acc[8];
    #pragma unroll
    for (int nt = 0; nt < 8; ++nt) acc[nt] = (f32x4){0.f, 0.f, 0.f, 0.f};

    auto stage = [&](const float4 r[4], int row_loc) {
        bf16x8 h0, l0, h1, l1;
        float fa[8] = {r[0].x, r[0].y, r[0].z, r[0].w, r[1].x, r[1].y, r[1].z, r[1].w};
        float fb[8] = {r[2].x, r[2].y, r[2].z, r[2].w, r[3].x, r[3].y, r[3].z, r[3].w};
        #pragma unroll
        for (int j = 0; j < 8; ++j) {
            short h = f2bf_trunc(fa[j]); h0[j] = h; l0[j] = f2bf_trunc(fa[j] - bf2f(h));
            h = f2bf_trunc(fb[j]);       h1[j] = h; l1[j] = f2bf_trunc(fb[j] - bf2f(h));
        }
        const int o = row_loc * A_LD + bk;
        *(bf16x8*)(Ah + o)     = h0;
        *(bf16x8*)(Ah + o + 8) = h1;
        *(bf16x8*)(Al + o)     = l0;
        *(bf16x8*)(Al + o + 8) = l1;
    };

    auto do_chunk = [&](int kg) {
        const int cl = kg & 3;   // chunk-local within the staged 128-k half
        const int ao = lm * A_LD + cl * 32 + quad * 8;
        const bf16x8 ah = *(const bf16x8*)(Ah + ao);
        const bf16x8 al = *(const bf16x8*)(Al + ao);
        const short* bp_h = WPh + kg * 512 + lane * 8;
        const short* bp_l = WPl + kg * 512 + lane * 8;
        bf16x8 bh0 = *(const bf16x8*)(bp_h);
        bf16x8 bl0 = *(const bf16x8*)(bp_l);
        bf16x8 bh1 = *(const bf16x8*)(bp_h + 4096);
        bf16x8 bl1 = *(const bf16x8*)(bp_l + 4096);
        #pragma unroll
        for (int nt = 0; nt < 8; ++nt) {
            bf16x8 bhn, bln;
            if (nt < 6) {
                bhn = *(const bf16x8*)(bp_h + (nt + 2) * 4096);
                bln = *(const bf16x8*)(bp_l + (nt + 2) * 4096);
            }
            acc[nt] = __builtin_amdgcn_mfma_f32_16x16x32_bf16(ah, bh0, acc[nt], 0, 0, 0);
            acc[nt] = __builtin_amdgcn_mfma_f32_16x16x32_bf16(ah, bl0, acc[nt], 0, 0, 0);
            acc[nt] = __builtin_amdgcn_mfma_f32_16x16x32_bf16(al, bh0, acc[nt], 0, 0, 0);
            bh0 = bh1; bl0 = bl1; bh1 = bhn; bl1 = bln;
        }
    };

    // ---- half 0: issue bursts, stage, compute chunks 0-2
    float4 ra[4], rb[4];
    #pragma unroll
    for (int j = 0; j < 4; ++j) ra[j] = ((const float4*)xp0)[j];
    #pragma unroll
    for (int j = 0; j < 4; ++j) rb[j] = ((const float4*)xp1)[j];
    stage(ra, brow_l);
    stage(rb, 8 + brow_l);
    do_chunk(0);
    do_chunk(1);
    do_chunk(2);

    // ---- issue half-1 bursts (in-flight across chunk 3's compute)
    float4 na[4], nb[4];
    #pragma unroll
    for (int j = 0; j < 4; ++j) na[j] = ((const float4*)(xp0 + 128))[j];
    #pragma unroll
    for (int j = 0; j < 4; ++j) nb[j] = ((const float4*)(xp1 + 128))[j];
    do_chunk(3);

    // ---- stage half 1 (single LDS buffer: in-order DS makes this safe)
    stage(na, brow_l);
    stage(nb, 8 + brow_l);
    do_chunk(4);
    do_chunk(5);
    do_chunk(6);
    do_chunk(7);

    // ---- epilogue: C/D layout col=lane&15, row=quad*4+reg
    #pragma unroll
    for (int r = 0; r < 4; ++r) {
        const int rg = wrow + quad * 4 + r;
        if (rg < N) {
            float* yp = y + (size_t)rg * 128 + lm;
            #pragma unroll
            for (int nt = 0; nt < 8; ++nt)
                yp[nt * 16] = acc[nt][r];
        }
    }
}

// ===========================================================================
// fused1: per node (one wave each):
//   agg = mean_{s in N(i)} y_l[s]; v = agg + b1 + y_r[i]; h = relu(normalize(v));
//   z[i] = [h @ W2_l | h @ W2_r]
// ===========================================================================
__global__ __launch_bounds__(256) void fused1_kernel(
    const float* __restrict__ y, const int* __restrict__ off, const int* __restrict__ nbr,
    const float* __restrict__ b1, const float* __restrict__ W2l, const float* __restrict__ W2r,
    float* __restrict__ z, int N)
{
    const int wave = threadIdx.x >> 6;
    const int lane = threadIdx.x & 63;
    const int i = blockIdx.x * 4 + wave;
    if (i >= N) return;

    const int beg = off[i];
    const int end = off[i + 1];
    const int deg = end - beg;

    const int dd = (deg < 64) ? deg : 64;
    int myn = (lane < dd) ? nbr[beg + lane] : 0;

    float acc = 0.f;
    int j = 0;
    for (; j + 1 < dd; j += 2) {
        const int s0 = __shfl(myn, j, 64);
        const int s1 = __shfl(myn, j + 1, 64);
        const float v0 = y[(size_t)s0 * 128 + lane];
        const float v1 = y[(size_t)s1 * 128 + lane];
        acc += v0 + v1;
    }
    if (j < dd) {
        const int s0 = __shfl(myn, j, 64);
        acc += y[(size_t)s0 * 128 + lane];
    }
    for (int q = beg + 64; q < end; ++q) {
        const int s = nbr[q];
        acc += y[(size_t)s * 128 + lane];
    }

    const float dinv = 1.0f / fmaxf((float)deg, 1.0f);
    float v = acc * dinv + b1[lane] + y[(size_t)i * 128 + 64 + lane];

    float ss = v * v;
    #pragma unroll
    for (int m = 32; m >= 1; m >>= 1) ss += __shfl_xor(ss, m, 64);
    const float inv = 1.0f / fmaxf(sqrtf(ss), 1e-12f);
    const float hv = fmaxf(v * inv, 0.f);

    const float4 wl = *(const float4*)(W2l + lane * 4);
    const float4 wr = *(const float4*)(W2r + lane * 4);
    float p0 = hv * wl.x, p1 = hv * wl.y, p2 = hv * wl.z, p3 = hv * wl.w;
    float p4 = hv * wr.x, p5 = hv * wr.y, p6 = hv * wr.z, p7 = hv * wr.w;

    const bool b0 = (lane & 1) != 0;
    float s0_ = b0 ? p0 : p4;
    float s1_ = b0 ? p1 : p5;
    float s2_ = b0 ? p2 : p6;
    float s3_ = b0 ? p3 : p7;
    float q0 = (b0 ? p4 : p0) + __shfl_xor(s0_, 1, 64);
    float q1 = (b0 ? p5 : p1) + __shfl_xor(s1_, 1, 64);
    float q2 = (b0 ? p6 : p2) + __shfl_xor(s2_, 1, 64);
    float q3 = (b0 ? p7 : p3) + __shfl_xor(s3_, 1, 64);
    const bool b1b = (lane & 2) != 0;
    float t0 = b1b ? q0 : q2;
    float t1 = b1b ? q1 : q3;
    float r0 = (b1b ? q2 : q0) + __shfl_xor(t0, 2, 64);
    float r1 = (b1b ? q3 : q1) + __shfl_xor(t1, 2, 64);
    const bool b2 = (lane & 4) != 0;
    float u0 = b2 ? r0 : r1;
    float zv = (b2 ? r1 : r0) + __shfl_xor(u0, 4, 64);
    zv += __shfl_xor(zv, 8, 64);
    zv += __shfl_xor(zv, 16, 64);
    zv += __shfl_xor(zv, 32, 64);
    const int ch = 4 * (lane & 1) + ((lane & 2)) + ((lane >> 2) & 1);
    if (lane < 8) z[(size_t)i * 8 + ch] = zv;
}

// ===========================================================================
// fused2: per node (one thread): out = normalize(mean z_l[nbr] + b2 + z_r[i])
// ===========================================================================
__global__ void fused2_kernel(const float* __restrict__ z, const int* __restrict__ off,
                              const int* __restrict__ nbr, const float* __restrict__ b2,
                              float* __restrict__ out, int N)
{
    const int i = blockIdx.x * blockDim.x + threadIdx.x;
    if (i >= N) return;
    const int beg = off[i];
    const int end = off[i + 1];
    float4 acc = make_float4(0.f, 0.f, 0.f, 0.f);
    for (int j = beg; j < end; ++j) {
        const int s = nbr[j];
        const float4 t = *(const float4*)(z + (size_t)s * 8);
        acc.x += t.x; acc.y += t.y; acc.z += t.z; acc.w += t.w;
    }
    const float dinv = 1.0f / fmaxf((float)(end - beg), 1.0f);
    const float4 r  = *(const float4*)(z + (size_t)i * 8 + 4);
    const float4 bb = *(const float4*)(b2);
    float4 o;
    o.x = acc.x * dinv + bb.x + r.x;
    o.y = acc.y * dinv + bb.y + r.y;
    o.z = acc.z * dinv + bb.z + r.z;
    o.w = acc.w * dinv + bb.w + r.w;
    const float ss = o.x * o.x + o.y * o.y + o.z * o.z + o.w * o.w;
    const float inv = 1.0f / fmaxf(sqrtf(ss), 1e-12f);
    o.x *= inv; o.y *= inv; o.z *= inv; o.w *= inv;
    *(float4*)(out + (size_t)i * 4) = o;
}

// ===========================================================================
extern "C" void kernel_launch(void* const* d_in, const int* in_sizes, int n_in,
                              void* d_out, int out_size, void* d_ws, size_t ws_size,
                              hipStream_t stream)
{
    const float* x    = (const float*)d_in[0];
    const int*   ei   = (const int*)d_in[1];
    const float* W1l  = (const float*)d_in[2];
    const float* b1l  = (const float*)d_in[3];
    const float* W1r  = (const float*)d_in[4];
    const float* W2l  = (const float*)d_in[5];
    const float* b2l  = (const float*)d_in[6];
    const float* W2r  = (const float*)d_in[7];
    float* out = (float*)d_out;

    const int N = in_sizes[0] / DIN;
    const int E = in_sizes[1] / 2;
    const int* src = ei;
    const int* dst = ei + E;
    const int nblk = (N + 255) / 256;

    // workspace layout
    char* ws = (char*)d_ws;
    size_t woff = 0;
    auto alloc = [&](size_t bytes) {
        void* p = ws + woff;
        woff += (bytes + 255) & ~(size_t)255;
        return p;
    };
    float* y        = (float*)alloc((size_t)N * 128 * 4);
    float* z        = (float*)alloc((size_t)N * 8 * 4);
    short* WPh      = (short*)alloc((size_t)128 * 256 * 2);
    short* WPl      = (short*)alloc((size_t)128 * 256 * 2);
    int*   cnt      = (int*)alloc((size_t)2 * N * 4);    // cnt + cursor contiguous
    int*   cursor   = cnt + N;
    int*   off      = (int*)alloc((size_t)(N + 1) * 4);
    int*   nbr      = (int*)alloc((size_t)E * 4);
    int*   blocksum = (int*)alloc((size_t)nblk * 4);
    int*   blockoff = (int*)alloc((size_t)nblk * 4);

    hipMemsetAsync(cnt, 0, (size_t)2 * N * 4, stream);

    // --- CSR build
    count_kernel<<<(E + 255) / 256, 256, 0, stream>>>(dst, cnt, E);
    scan_a_kernel<<<nblk, 256, 0, stream>>>(cnt, blocksum, N);
    scan_b_kernel<<<1, 1024, 0, stream>>>(blocksum, blockoff, nblk);
    scan_c_kernel<<<nblk, 256, 0, stream>>>(cnt, blockoff, off, N);
    fill_kernel<<<(E + 255) / 256, 256, 0, stream>>>(src, dst, off, cursor, nbr, E);

    // --- layer 1 GEMM
    wprep_kernel<<<128, 256, 0, stream>>>(W1l, W1r, WPh, WPl);
    gemm1_mfma<<<(N + 63) / 64, 256, 0, stream>>>(x, WPh, WPl, y, N);

    // --- fused aggregate + norm + relu + gemm2
    fused1_kernel<<<(N + 3) / 4, 256, 0, stream>>>(y, off, nbr, b1l, W2l, W2r, z, N);

    // --- fused aggregate + norm (layer 2)
    fused2_kernel<<<(N + 255) / 256, 256, 0, stream>>>(z, off, nbr, b2l, out, N);
}